// Round 8
// baseline (99.637 us; speedup 1.0000x reference)
//
#include <hip/hip_runtime.h>

#define NT 256
#define W 56
#define HW 3136            // 56*56
#define KSEL 30
#define CAP 160

typedef float v2f __attribute__((ext_vector_type(2)));

__device__ __forceinline__ v2f vfma(v2f a, v2f b, v2f c) {
#if __has_builtin(__builtin_elementwise_fma)
    return __builtin_elementwise_fma(a, b, c);
#else
    v2f r; r.x = fmaf(a.x, b.x, c.x); r.y = fmaf(a.y, b.y, c.y); return r;
#endif
}

__global__ __launch_bounds__(NT, 8) void topk_spatial_kernel(
    const float* __restrict__ x,
    const float* __restrict__ wgt,
    const float* __restrict__ bias,
    float* __restrict__ out,
    int C)
{
    __shared__ unsigned int smax[NT];
    __shared__ int          c_idx[CAP];
    __shared__ double       c_sd[CAP];
    __shared__ unsigned int keepw[HW / 32];   // 98 words
    __shared__ unsigned int s_T16;
    __shared__ int s_cnt;

    const int tid = threadIdx.x;
    const int bc  = blockIdx.x;              // b*C + c
    const int ci  = bc % C;

    const float* xp = x   + (size_t)bc * HW;
    float*       op = out + (size_t)bc * HW;

    const float* wpt = wgt + (size_t)ci * 9;
    const float wk[3][3] = { { wpt[0], wpt[1], wpt[2] },
                             { wpt[3], wpt[4], wpt[5] },
                             { wpt[6], wpt[7], wpt[8] } };
    const float bv = bias[ci];

    if (tid < HW / 32) keepw[tid] = 0u;
    if (tid == 255) s_cnt = 0;

    // ---- thread -> 4x4 output tile: 16 lanes per row-group (14 active),
    //      so row-groups never straddle a wave (shuffle halo stays in-wave)
    const int m_ = tid & 15;           // quad col (0..13 active)
    const int g_ = tid >> 4;           // row group (0..13 active)
    const bool active = (m_ < 14) && (g_ < 14);
    const int mq = (m_ < 14) ? m_ : 13;            // clamped for idle lanes
    const int gq = (g_ < 14) ? g_ : 13;

    // ---- conv straight from global (L1-hot vertical reuse), halo via shfl
    unsigned int k32[16];
    unsigned int mx = 0u;
    {
        v2f accL[4], accH[4];
        #pragma unroll
        for (int k = 0; k < 4; ++k) { accL[k] = v2f{bv, bv}; accH[k] = v2f{bv, bv}; }

        const int cb = 4 * mq;
        #pragma unroll
        for (int dr = 0; dr < 6; ++dr) {
            const int rr = 4 * gq - 1 + dr;
            const int ra = (rr < 0) ? 0 : ((rr > 55) ? 55 : rr);
            const bool rok = (rr >= 0) && (rr < 56);
            float4 vm = *reinterpret_cast<const float4*>(xp + ra * W + cb);
            vm.x = rok ? vm.x : 0.0f;
            vm.y = rok ? vm.y : 0.0f;
            vm.z = rok ? vm.z : 0.0f;
            vm.w = rok ? vm.w : 0.0f;
            // halo cols from neighbor lanes (all lanes execute the shfl)
            const float lraw = __shfl_up(vm.w, 1);
            const float rraw = __shfl_down(vm.x, 1);
            const float vl = (m_ == 0)  ? 0.0f : lraw;
            const float vr = (m_ == 13) ? 0.0f : rraw;

            const v2f p0 = { vl,   vm.x };
            const v2f p1 = { vm.x, vm.y };
            const v2f p2 = { vm.y, vm.z };
            const v2f p3 = { vm.z, vm.w };
            const v2f p4 = { vm.w, vr   };
            #pragma unroll
            for (int k = 0; k < 4; ++k) {
                const int kr = dr - k;                       // kernel row
                if (kr >= 0 && kr < 3) {
                    const v2f wA = { wk[kr][0], wk[kr][0] };
                    const v2f wB = { wk[kr][1], wk[kr][1] };
                    const v2f wC = { wk[kr][2], wk[kr][2] };
                    accL[k] = vfma(wA, p0, accL[k]);
                    accL[k] = vfma(wB, p1, accL[k]);
                    accL[k] = vfma(wC, p2, accL[k]);
                    accH[k] = vfma(wA, p2, accH[k]);
                    accH[k] = vfma(wB, p3, accH[k]);
                    accH[k] = vfma(wC, p4, accH[k]);
                }
            }
        }

        if (active) {
            #pragma unroll
            for (int k = 0; k < 4; ++k) {
                const float sv[4] = { accL[k].x, accL[k].y, accH[k].x, accH[k].y };
                #pragma unroll
                for (int j = 0; j < 4; ++j) {
                    const unsigned int bb = __float_as_uint(sv[j]);
                    const unsigned int key = ((int)bb < 0) ? ~bb : (bb | 0x80000000u);
                    k32[k * 4 + j] = key;
                    mx = (key > mx) ? key : mx;
                }
            }
        } else {
            #pragma unroll
            for (int kk = 0; kk < 16; ++kk) k32[kk] = 0u;
        }
    }

    smax[tid] = mx;
    __syncthreads();                                         // B2

    // ---- wave 0: binary search on hi-16 key bits, ballot+popcount ----
    if (tid < 64) {
        const unsigned int m0 = smax[tid]       >> 16;
        const unsigned int m1 = smax[tid + 64]  >> 16;
        const unsigned int m2 = smax[tid + 128] >> 16;
        const unsigned int m3 = smax[tid + 192] >> 16;
        unsigned int lo = 0u, hi = 65536u;   // cnt(>=lo) >= 30 > cnt(>=hi)
        while (hi - lo > 1u) {
            const unsigned int mid = (lo + hi) >> 1;
            const int c = (m0 >= mid) + (m1 >= mid) + (m2 >= mid) + (m3 >= mid);
            const unsigned long long b0 = __ballot(c & 1);
            const unsigned long long b1 = __ballot(c & 2);
            const unsigned long long b2 = __ballot(c & 4);
            const int cnt = __popcll(b0) + 2 * __popcll(b1) + 4 * __popcll(b2);
            if (cnt >= KSEL) { lo = mid; if (cnt <= 48) break; }
            else hi = mid;
        }
        if (tid == 0) s_T16 = lo;
    }
    __syncthreads();                                         // B3

    // ---- widen cut by absolute margin 1e-4 in float domain ----
    const unsigned int binkey = s_T16 << 16;
    const float Tf = (binkey & 0x80000000u)
                         ? __uint_as_float(binkey ^ 0x80000000u)
                         : __uint_as_float(~binkey);
    const float Tm = Tf - 1e-4f;
    const unsigned int tb    = __float_as_uint(Tm);
    const unsigned int TmKey = ((int)tb < 0) ? ~tb : (tb | 0x80000000u);

    // ---- gather candidate indices ----
    if (active) {
        #pragma unroll
        for (int kk = 0; kk < 16; ++kk) {
            if (k32[kk] >= TmKey) {
                const int slot = atomicAdd(&s_cnt, 1);
                if (slot < CAP)
                    c_idx[slot] = (4 * g_ + (kk >> 2)) * W + 4 * m_ + (kk & 3);
            }
        }
    }
    __syncthreads();                                         // B4

    // ---- f64 recompute for candidates from global (L1-hot), np fma order ----
    const int E = (s_cnt < CAP) ? s_cnt : CAP;
    if (tid < E) {
        const int i  = c_idx[tid];
        const int y  = i / W;
        const int xc = i - y * W;
        double s = (double)bv;
        #pragma unroll
        for (int dy = -1; dy <= 1; ++dy) {
            #pragma unroll
            for (int dx = -1; dx <= 1; ++dx) {
                const int yy = y + dy, xx = xc + dx;
                const int ya = (yy < 0) ? 0 : ((yy > 55) ? 55 : yy);
                const int xa = (xx < 0) ? 0 : ((xx > 55) ? 55 : xx);
                const float xv = xp[ya * W + xa];
                const bool ok = ((unsigned)yy < 56u) && ((unsigned)xx < 56u);
                s = fma((double)wk[dy + 1][dx + 1], ok ? (double)xv : 0.0, s);
            }
        }
        c_sd[tid] = s;
    }
    __syncthreads();                                         // B5

    // ---- exact rank among candidates: (s64 desc, idx asc); keep rank<K ----
    if (tid < E) {
        const double se = c_sd[tid];
        const int    ei = c_idx[tid];
        int rank = 0;
        for (int j = 0; j < E; ++j) {
            const double sj = c_sd[j];
            const int    ji = c_idx[j];
            rank += (sj > se) || (sj == se && ji < ei);
        }
        if (rank < KSEL) atomicOr(&keepw[ei >> 5], 1u << (ei & 31));
    }
    __syncthreads();                                         // B6

    // ---- output: reload own quads from global (L1 hit), mask, store ----
    if (active) {
        #pragma unroll
        for (int k = 0; k < 4; ++k) {
            const int ib = (4 * g_ + k) * W + 4 * m_;        // ib % 4 == 0
            float4 v = *reinterpret_cast<const float4*>(xp + ib);
            const unsigned int bits = keepw[ib >> 5] >> (ib & 31);
            v.x = (bits & 1u) ? v.x : 0.0f;
            v.y = (bits & 2u) ? v.y : 0.0f;
            v.z = (bits & 4u) ? v.z : 0.0f;
            v.w = (bits & 8u) ? v.w : 0.0f;
            *reinterpret_cast<float4*>(&op[ib]) = v;
        }
    }
}

extern "C" void kernel_launch(void* const* d_in, const int* in_sizes, int n_in,
                              void* d_out, int out_size, void* d_ws, size_t ws_size,
                              hipStream_t stream) {
    const float* x  = (const float*)d_in[0];
    const float* w  = (const float*)d_in[1];
    const float* b  = (const float*)d_in[2];
    float* out      = (float*)d_out;

    const int C  = in_sizes[2];            // 384
    const int BC = in_sizes[0] / HW;       // b*c = 12288

    topk_spatial_kernel<<<BC, NT, 0, stream>>>(x, w, b, out, C);
}

// Round 9
// 84.663 us; speedup vs baseline: 1.1769x; 1.1769x over previous
//
#include <hip/hip_runtime.h>

#define NT 256
#define W 56
#define HW 3136            // 56*56
#define KSEL 30
#define CAP 160

typedef float v2f __attribute__((ext_vector_type(2)));

__device__ __forceinline__ v2f vfma(v2f a, v2f b, v2f c) {
#if __has_builtin(__builtin_elementwise_fma)
    return __builtin_elementwise_fma(a, b, c);
#else
    v2f r; r.x = fmaf(a.x, b.x, c.x); r.y = fmaf(a.y, b.y, c.y); return r;
#endif
}

__global__ __launch_bounds__(NT, 8) void topk_spatial_kernel(
    const float* __restrict__ x,
    const float* __restrict__ wgt,
    const float* __restrict__ bias,
    float* __restrict__ out,
    int C)
{
    __shared__ float4       hsA[14][14];   // row 4g+3 quads (top halo of g+1)
    __shared__ float4       hsB[14][14];   // row 4g   quads (bottom halo of g-1)
    __shared__ unsigned int smax[NT];
    __shared__ int          c_idx[CAP];
    __shared__ double       c_sd[CAP];
    __shared__ unsigned int keepw[HW / 32];   // 98 words
    __shared__ unsigned int s_T16;
    __shared__ int s_cnt;

    const int tid = threadIdx.x;
    const int bc  = blockIdx.x;              // b*C + c
    const int ci  = bc % C;

    const float* xp = x   + (size_t)bc * HW;
    float*       op = out + (size_t)bc * HW;

    const float* wpt = wgt + (size_t)ci * 9;
    const float wk[3][3] = { { wpt[0], wpt[1], wpt[2] },
                             { wpt[3], wpt[4], wpt[5] },
                             { wpt[6], wpt[7], wpt[8] } };
    const float bv = bias[ci];

    // thread -> 4x4 tile: 16 lanes per row-group (14 active) so the
    // horizontal halo shuffles never cross a row-group boundary in-wave
    const int m_ = tid & 15;           // quad col (0..13 active)
    const int g_ = tid >> 4;           // row group (0..13 active)
    const bool active = (m_ < 14) && (g_ < 14);
    const int mq = (m_ < 14) ? m_ : 13;
    const int gq = (g_ < 14) ? g_ : 13;

    if (tid < HW / 32) keepw[tid] = 0u;
    if (tid == 255) s_cnt = 0;

    // ---- load own 4 rows ONCE from global; publish halo rows to LDS ----
    float4 xm[4];
    #pragma unroll
    for (int k = 0; k < 4; ++k) xm[k] = float4{0.f, 0.f, 0.f, 0.f};
    if (active) {
        #pragma unroll
        for (int k = 0; k < 4; ++k)
            xm[k] = *reinterpret_cast<const float4*>(xp + (4 * g_ + k) * W + 4 * m_);
        hsA[g_][m_] = xm[3];
        hsB[g_][m_] = xm[0];
    }
    __syncthreads();                                         // B1

    // ---- conv: 6-row window = 1 LDS halo + 4 reg rows + 1 LDS halo ----
    unsigned int k32[16];
    unsigned int mx = 0u;
    {
        v2f accL[4], accH[4];
        #pragma unroll
        for (int k = 0; k < 4; ++k) { accL[k] = v2f{bv, bv}; accH[k] = v2f{bv, bv}; }

        const float4 haloT = hsA[(gq > 0) ? gq - 1 : 0][mq];
        const float4 haloB = hsB[(gq < 13) ? gq + 1 : 13][mq];

        #pragma unroll
        for (int dr = 0; dr < 6; ++dr) {
            float4 vm;
            if (dr == 0)      vm = haloT;
            else if (dr == 5) vm = haloB;
            else              vm = xm[dr - 1];
            // zero out-of-image halo rows
            if (dr == 0 && g_ == 0)  vm = float4{0.f, 0.f, 0.f, 0.f};
            if (dr == 5 && g_ == 13) vm = float4{0.f, 0.f, 0.f, 0.f};

            // halo cols from neighbor lanes (all lanes execute the shfl)
            const float lraw = __shfl_up(vm.w, 1);
            const float rraw = __shfl_down(vm.x, 1);
            const float vl = (m_ == 0)  ? 0.0f : lraw;
            const float vr = (m_ == 13) ? 0.0f : rraw;

            const v2f p0 = { vl,   vm.x };
            const v2f p1 = { vm.x, vm.y };
            const v2f p2 = { vm.y, vm.z };
            const v2f p3 = { vm.z, vm.w };
            const v2f p4 = { vm.w, vr   };
            #pragma unroll
            for (int k = 0; k < 4; ++k) {
                const int kr = dr - k;                       // kernel row
                if (kr >= 0 && kr < 3) {
                    const v2f wA = { wk[kr][0], wk[kr][0] };
                    const v2f wB = { wk[kr][1], wk[kr][1] };
                    const v2f wC = { wk[kr][2], wk[kr][2] };
                    accL[k] = vfma(wA, p0, accL[k]);
                    accL[k] = vfma(wB, p1, accL[k]);
                    accL[k] = vfma(wC, p2, accL[k]);
                    accH[k] = vfma(wA, p2, accH[k]);
                    accH[k] = vfma(wB, p3, accH[k]);
                    accH[k] = vfma(wC, p4, accH[k]);
                }
            }
        }

        if (active) {
            #pragma unroll
            for (int k = 0; k < 4; ++k) {
                const float sv[4] = { accL[k].x, accL[k].y, accH[k].x, accH[k].y };
                #pragma unroll
                for (int j = 0; j < 4; ++j) {
                    const unsigned int bb = __float_as_uint(sv[j]);
                    const unsigned int key = ((int)bb < 0) ? ~bb : (bb | 0x80000000u);
                    k32[k * 4 + j] = key;
                    mx = (key > mx) ? key : mx;
                }
            }
        } else {
            #pragma unroll
            for (int kk = 0; kk < 16; ++kk) k32[kk] = 0u;
        }
    }

    smax[tid] = mx;
    __syncthreads();                                         // B2

    // ---- wave 0: binary search on hi-16 key bits, ballot+popcount ----
    if (tid < 64) {
        const unsigned int m0 = smax[tid]       >> 16;
        const unsigned int m1 = smax[tid + 64]  >> 16;
        const unsigned int m2 = smax[tid + 128] >> 16;
        const unsigned int m3 = smax[tid + 192] >> 16;
        unsigned int lo = 0u, hi = 65536u;   // cnt(>=lo) >= 30 > cnt(>=hi)
        while (hi - lo > 1u) {
            const unsigned int mid = (lo + hi) >> 1;
            const int c = (m0 >= mid) + (m1 >= mid) + (m2 >= mid) + (m3 >= mid);
            const unsigned long long b0 = __ballot(c & 1);
            const unsigned long long b1 = __ballot(c & 2);
            const unsigned long long b2 = __ballot(c & 4);
            const int cnt = __popcll(b0) + 2 * __popcll(b1) + 4 * __popcll(b2);
            if (cnt >= KSEL) { lo = mid; if (cnt <= 48) break; }
            else hi = mid;
        }
        if (tid == 0) s_T16 = lo;
    }
    __syncthreads();                                         // B3

    // ---- widen cut by absolute margin 1e-4 in float domain ----
    const unsigned int binkey = s_T16 << 16;
    const float Tf = (binkey & 0x80000000u)
                         ? __uint_as_float(binkey ^ 0x80000000u)
                         : __uint_as_float(~binkey);
    const float Tm = Tf - 1e-4f;
    const unsigned int tb    = __float_as_uint(Tm);
    const unsigned int TmKey = ((int)tb < 0) ? ~tb : (tb | 0x80000000u);

    // ---- gather candidate indices ----
    if (active) {
        #pragma unroll
        for (int kk = 0; kk < 16; ++kk) {
            if (k32[kk] >= TmKey) {
                const int slot = atomicAdd(&s_cnt, 1);
                if (slot < CAP)
                    c_idx[slot] = (4 * g_ + (kk >> 2)) * W + 4 * m_ + (kk & 3);
            }
        }
    }
    __syncthreads();                                         // B4

    // ---- f64 recompute for candidates from global (L2-hot), np fma order ----
    const int E = (s_cnt < CAP) ? s_cnt : CAP;
    if (tid < E) {
        const int i  = c_idx[tid];
        const int y  = i / W;
        const int xc = i - y * W;
        double s = (double)bv;
        #pragma unroll
        for (int dy = -1; dy <= 1; ++dy) {
            #pragma unroll
            for (int dx = -1; dx <= 1; ++dx) {
                const int yy = y + dy, xx = xc + dx;
                const int ya = (yy < 0) ? 0 : ((yy > 55) ? 55 : yy);
                const int xa = (xx < 0) ? 0 : ((xx > 55) ? 55 : xx);
                const float xv = xp[ya * W + xa];
                const bool ok = ((unsigned)yy < 56u) && ((unsigned)xx < 56u);
                s = fma((double)wk[dy + 1][dx + 1], ok ? (double)xv : 0.0, s);
            }
        }
        c_sd[tid] = s;
    }
    __syncthreads();                                         // B5

    // ---- exact rank among candidates: (s64 desc, idx asc); keep rank<K ----
    if (tid < E) {
        const double se = c_sd[tid];
        const int    ei = c_idx[tid];
        int rank = 0;
        for (int j = 0; j < E; ++j) {
            const double sj = c_sd[j];
            const int    ji = c_idx[j];
            rank += (sj > se) || (sj == se && ji < ei);
        }
        if (rank < KSEL) atomicOr(&keepw[ei >> 5], 1u << (ei & 31));
    }
    __syncthreads();                                         // B6

    // ---- output straight from registers ----
    if (active) {
        #pragma unroll
        for (int k = 0; k < 4; ++k) {
            const int ib = (4 * g_ + k) * W + 4 * m_;        // ib % 4 == 0
            const unsigned int bits = keepw[ib >> 5] >> (ib & 31);
            float4 v = xm[k];
            v.x = (bits & 1u) ? v.x : 0.0f;
            v.y = (bits & 2u) ? v.y : 0.0f;
            v.z = (bits & 4u) ? v.z : 0.0f;
            v.w = (bits & 8u) ? v.w : 0.0f;
            *reinterpret_cast<float4*>(&op[ib]) = v;
        }
    }
}

extern "C" void kernel_launch(void* const* d_in, const int* in_sizes, int n_in,
                              void* d_out, int out_size, void* d_ws, size_t ws_size,
                              hipStream_t stream) {
    const float* x  = (const float*)d_in[0];
    const float* w  = (const float*)d_in[1];
    const float* b  = (const float*)d_in[2];
    float* out      = (float*)d_out;

    const int C  = in_sizes[2];            // 384
    const int BC = in_sizes[0] / HW;       // b*c = 12288

    topk_spatial_kernel<<<BC, NT, 0, stream>>>(x, w, b, out, C);
}